// Round 6
// baseline (129.953 us; speedup 1.0000x reference)
//
#include <hip/hip_runtime.h>
#include <cstdint>
#include <cstddef>

#define RANK 16

// ---------------------------------------------------------------------------
// Kernel 1: mix LoRA factors with per-(batch,split) skill weights.
//   Am[b][k][r] = sum_s w[b][q][s] * la[q][s][d][r],   k = q*512 + d
//                 (r-contiguous so phase A can s_load_dwordx16 a whole row)
//   Bm[b][r][o] = 2 * sum_s w[b][q][s] * lb[q][s][r][dd], o = q*512 + dd
// (scaling = lora_alpha/rank = 2, folded into Bm)
// ---------------------------------------------------------------------------
__global__ __launch_bounds__(256) void skilled_lora_mix(
    const float* __restrict__ w,   // [8][4][8]
    const float* __restrict__ la,  // [4][8][512][16]
    const float* __restrict__ lb,  // [4][8][16][512]
    float* __restrict__ Am,        // [8][2048][16]
    float* __restrict__ Bm)        // [8][16][2048], pre-scaled by 2
{
  const int j = blockIdx.x * 256 + threadIdx.x;
  if (j < 65536) {
    const int r0 = (j & 3) * 4;
    const int k  = (j >> 2) & 2047;
    const int b  = j >> 13;
    const int q  = k >> 9;
    const int d  = k & 511;
    const float* wb = w + (b * 4 + q) * 8;
    float4 acc = make_float4(0.f, 0.f, 0.f, 0.f);
#pragma unroll
    for (int s = 0; s < 8; ++s) {
      const float ws = wb[s];
      const float4 v = *reinterpret_cast<const float4*>(
          la + (size_t)(((q * 8 + s) * 512 + d) * 16 + r0));
      acc.x = fmaf(ws, v.x, acc.x);
      acc.y = fmaf(ws, v.y, acc.y);
      acc.z = fmaf(ws, v.z, acc.z);
      acc.w = fmaf(ws, v.w, acc.w);
    }
    *reinterpret_cast<float4*>(Am + (size_t)((b * 2048 + k) * 16 + r0)) = acc;
  } else {
    const int jj = j - 65536;
    const int o  = (jj & 511) * 4;
    const int r  = (jj >> 9) & 15;
    const int b  = jj >> 13;
    const int q  = o >> 9;
    const int dd = o & 511;
    const float* wb = w + (b * 4 + q) * 8;
    float4 acc = make_float4(0.f, 0.f, 0.f, 0.f);
#pragma unroll
    for (int s = 0; s < 8; ++s) {
      const float ws = wb[s];
      const float4 v = *reinterpret_cast<const float4*>(
          lb + (size_t)(((q * 8 + s) * 16 + r) * 512 + dd));
      acc.x = fmaf(ws, v.x, acc.x);
      acc.y = fmaf(ws, v.y, acc.y);
      acc.z = fmaf(ws, v.z, acc.z);
      acc.w = fmaf(ws, v.w, acc.w);
    }
    acc.x *= 2.f; acc.y *= 2.f; acc.z *= 2.f; acc.w *= 2.f;
    *reinterpret_cast<float4*>(Bm + (size_t)((b * 16 + r) * 2048 + o)) = acc;
  }
}

// ---------------------------------------------------------------------------
// Kernel 2 (phase A, v3): tmp[b][row][r] = sum_k X[b][row][k] * Am[b][k][r]
//
// ROUND-6 RESTRUCTURE: round-5 version was LDS-pipe-bound (4x ds_read_b128
// of the wave-uniform At row per kk ~ 1722 LDS cyc vs 1024 VALU cyc/chunk).
// Now the whole wave walks the SAME kk (lane = row, 64 rows/block):
//   - Am[b][k][r] address is wave-uniform -> s_load_dwordx16 (scalar pipe),
//     FMAs read the 16 A values from SGPRs (1 SGPR operand per VALU, legal).
//   - LDS holds only X: 1 ds_read_b32 per kk, banks = lane%32 (2-way, free).
// Block: 512 thr = 8 waves, each wave owns a 256-k window; 64 rows.
// LDS 67 KB -> 2 blocks/CU -> 16 waves/CU = 4/SIMD.
// bufX region is reused (after a barrier) for the 8-way cross-wave reduce.
// ---------------------------------------------------------------------------
#define ROWS3 64
#define KWIN3 256
#define KCH3  32
#define XS    33   // bufX row stride (odd -> lane%32 banks, 2-way, free)
#define PS    17   // part row stride (odd -> conflict-free reduce)

__global__ __launch_bounds__(512, 2) void lora_phase_a(
    const float* __restrict__ X,    // [8][2048][2048]
    const float* __restrict__ Am,   // [8][2048][16]
    float* __restrict__ tmp)        // [8][2048][16]
{
  __shared__ float lds[8 * ROWS3 * XS];   // 16896 floats = 67.6 KB

  const int tid  = threadIdx.x;
  const int lane = tid & 63;
  const int wv   = tid >> 6;              // 0..7
  const int b    = blockIdx.x >> 5;       // 8 batches x 32 row-tiles
  const int row0 = (blockIdx.x & 31) * ROWS3;
  const int kw   = wv * KWIN3;

  float* bufX = lds + wv * (ROWS3 * XS);

  const float* Xb = X + ((size_t)(b * 2048 + row0)) * 2048 + kw;
  const float* Ab = Am + ((size_t)b * 2048 + kw) * RANK;

  const int srow = lane >> 3;             // staging: 8 rows x 8 col-groups
  const int scol = (lane & 7) * 4;

  float acc[RANK];
#pragma unroll
  for (int r = 0; r < RANK; ++r) acc[r] = 0.f;

  for (int c = 0; c < KWIN3 / KCH3; ++c) {   // 8 chunks of 32 k
    // ---- stage 64 rows x 32 k (b128 global loads, 128B segments) ----
#pragma unroll
    for (int i = 0; i < 8; ++i) {
      const int row = i * 8 + srow;
      const float4 v = *reinterpret_cast<const float4*>(
          Xb + (size_t)row * 2048 + c * KCH3 + scol);
      float* d = bufX + row * XS + scol;
      d[0] = v.x; d[1] = v.y; d[2] = v.z; d[3] = v.w;
    }
    // wave-private buffer + same-wave in-order DS: no barrier needed.

    // ---- compute: 32 kk, A row from SGPRs, x from LDS ----
    const float* xr = bufX + lane * XS;
    const float* Ac = Ab + (size_t)(c * KCH3) * RANK;
#pragma unroll 4
    for (int kk = 0; kk < KCH3; ++kk) {
      const float x = xr[kk];
      const float* Ar = Ac + kk * RANK;    // wave-uniform -> s_load
#pragma unroll
      for (int r = 0; r < RANK; ++r)
        acc[r] = fmaf(x, Ar[r], acc[r]);
    }
  }

  // ---- cross-wave reduce: park acc in (reused) LDS, then 8-way sum ----
  __syncthreads();                          // all waves done reading bufX
  float* part = lds;                        // [8 waves][64 rows][stride 17]
  {
    float* pp = part + (wv * ROWS3 + lane) * PS;
#pragma unroll
    for (int r = 0; r < RANK; ++r) pp[r] = acc[r];
  }
  __syncthreads();

#pragma unroll
  for (int v = tid; v < ROWS3 * RANK; v += 512) {
    const int row = v >> 4;
    const int r   = v & 15;
    float s = 0.f;
#pragma unroll
    for (int p = 0; p < 8; ++p) s += part[(p * ROWS3 + row) * PS + r];
    tmp[((size_t)(b * 2048 + row0 + row)) * RANK + r] = s;
  }
}

// ---------------------------------------------------------------------------
// Kernel 3 (phase B): out[b][row][o] = sum_r tmp[b][row][r] * Bm[b][r][o]
// ROUND-6: grid 512 -> 1024 (32 rows/block) for 4 waves/SIMD of TLP; round 5
// at 2 waves/SIMD was latency-bound at 2.5 TB/s (write ceiling ~7 TB/s per
// the harness fill kernel). B-slab reload cost: +64 MB L2 reads (~2 us).
// ---------------------------------------------------------------------------
__global__ __launch_bounds__(256, 2) void lora_phase_b(
    const float* __restrict__ tmp,  // [8][2048][16]
    const float* __restrict__ Bm,   // [8][16][2048] (pre-scaled by 2)
    float* __restrict__ out)        // [8][2048][2048]
{
  const int tid  = threadIdx.x;
  const int b    = blockIdx.x >> 7;          // 8 batches x 128 blocks
  const int oh   = (blockIdx.x >> 6) & 1;    // column half
  const int rt   = blockIdx.x & 63;          // row tile
  const int row0 = rt * 32;
  const int o0   = oh * 1024 + tid * 4;

  const float* Bb = Bm + (size_t)b * (RANK * 2048) + o0;
  float4 B4[RANK];
#pragma unroll
  for (int r = 0; r < RANK; ++r)
    B4[r] = *reinterpret_cast<const float4*>(Bb + (size_t)r * 2048);

  const float* tp = tmp + ((size_t)(b * 2048 + row0)) * RANK;
  float* op = out + ((size_t)(b * 2048 + row0)) * 2048 + o0;

#pragma unroll 4
  for (int rr = 0; rr < 32; ++rr) {
    const float4 t0 = *reinterpret_cast<const float4*>(tp + rr * RANK);
    const float4 t1 = *reinterpret_cast<const float4*>(tp + rr * RANK + 4);
    const float4 t2 = *reinterpret_cast<const float4*>(tp + rr * RANK + 8);
    const float4 t3 = *reinterpret_cast<const float4*>(tp + rr * RANK + 12);
    float4 a = make_float4(0.f, 0.f, 0.f, 0.f);
    a.x = fmaf(t0.x, B4[0].x, a.x);  a.y = fmaf(t0.x, B4[0].y, a.y);
    a.z = fmaf(t0.x, B4[0].z, a.z);  a.w = fmaf(t0.x, B4[0].w, a.w);
    a.x = fmaf(t0.y, B4[1].x, a.x);  a.y = fmaf(t0.y, B4[1].y, a.y);
    a.z = fmaf(t0.y, B4[1].z, a.z);  a.w = fmaf(t0.y, B4[1].w, a.w);
    a.x = fmaf(t0.z, B4[2].x, a.x);  a.y = fmaf(t0.z, B4[2].y, a.y);
    a.z = fmaf(t0.z, B4[2].z, a.z);  a.w = fmaf(t0.z, B4[2].w, a.w);
    a.x = fmaf(t0.w, B4[3].x, a.x);  a.y = fmaf(t0.w, B4[3].y, a.y);
    a.z = fmaf(t0.w, B4[3].z, a.z);  a.w = fmaf(t0.w, B4[3].w, a.w);
    a.x = fmaf(t1.x, B4[4].x, a.x);  a.y = fmaf(t1.x, B4[4].y, a.y);
    a.z = fmaf(t1.x, B4[4].z, a.z);  a.w = fmaf(t1.x, B4[4].w, a.w);
    a.x = fmaf(t1.y, B4[5].x, a.x);  a.y = fmaf(t1.y, B4[5].y, a.y);
    a.z = fmaf(t1.y, B4[5].z, a.z);  a.w = fmaf(t1.y, B4[5].w, a.w);
    a.x = fmaf(t1.z, B4[6].x, a.x);  a.y = fmaf(t1.z, B4[6].y, a.y);
    a.z = fmaf(t1.z, B4[6].z, a.z);  a.w = fmaf(t1.z, B4[6].w, a.w);
    a.x = fmaf(t1.w, B4[7].x, a.x);  a.y = fmaf(t1.w, B4[7].y, a.y);
    a.z = fmaf(t1.w, B4[7].z, a.z);  a.w = fmaf(t1.w, B4[7].w, a.w);
    a.x = fmaf(t2.x, B4[8].x, a.x);  a.y = fmaf(t2.x, B4[8].y, a.y);
    a.z = fmaf(t2.x, B4[8].z, a.z);  a.w = fmaf(t2.x, B4[8].w, a.w);
    a.x = fmaf(t2.y, B4[9].x, a.x);  a.y = fmaf(t2.y, B4[9].y, a.y);
    a.z = fmaf(t2.y, B4[9].z, a.z);  a.w = fmaf(t2.y, B4[9].w, a.w);
    a.x = fmaf(t2.z, B4[10].x, a.x); a.y = fmaf(t2.z, B4[10].y, a.y);
    a.z = fmaf(t2.z, B4[10].z, a.z); a.w = fmaf(t2.z, B4[10].w, a.w);
    a.x = fmaf(t2.w, B4[11].x, a.x); a.y = fmaf(t2.w, B4[11].y, a.y);
    a.z = fmaf(t2.w, B4[11].z, a.z); a.w = fmaf(t2.w, B4[11].w, a.w);
    a.x = fmaf(t3.x, B4[12].x, a.x); a.y = fmaf(t3.x, B4[12].y, a.y);
    a.z = fmaf(t3.x, B4[12].z, a.z); a.w = fmaf(t3.x, B4[12].w, a.w);
    a.x = fmaf(t3.y, B4[13].x, a.x); a.y = fmaf(t3.y, B4[13].y, a.y);
    a.z = fmaf(t3.y, B4[13].z, a.z); a.w = fmaf(t3.y, B4[13].w, a.w);
    a.x = fmaf(t3.z, B4[14].x, a.x); a.y = fmaf(t3.z, B4[14].y, a.y);
    a.z = fmaf(t3.z, B4[14].z, a.z); a.w = fmaf(t3.z, B4[14].w, a.w);
    a.x = fmaf(t3.w, B4[15].x, a.x); a.y = fmaf(t3.w, B4[15].y, a.y);
    a.z = fmaf(t3.w, B4[15].z, a.z); a.w = fmaf(t3.w, B4[15].w, a.w);
    *reinterpret_cast<float4*>(op + (size_t)rr * 2048) = a;
  }
}

// ---------------------------------------------------------------------------
extern "C" void kernel_launch(void* const* d_in, const int* in_sizes, int n_in,
                              void* d_out, int out_size, void* d_ws, size_t ws_size,
                              hipStream_t stream) {
  const float* input = (const float*)d_in[0];   // [8][2048][2048]
  const float* w     = (const float*)d_in[1];   // [8][4][8]
  const float* la    = (const float*)d_in[2];   // [4][8][512][16]
  const float* lb    = (const float*)d_in[3];   // [4][8][16][512]
  float* outp = (float*)d_out;

  float* Am  = (float*)d_ws;                    // 262144 floats (1 MB)
  float* Bm  = Am + 8 * 2048 * RANK;            // 262144 floats (1 MB)
  float* tmp = Bm + 8 * RANK * 2048;            // 262144 floats (1 MB)

  skilled_lora_mix<<<512, 256, 0, stream>>>(w, la, lb, Am, Bm);
  lora_phase_a<<<256, 512, 0, stream>>>(input, Am, tmp);
  lora_phase_b<<<1024, 256, 0, stream>>>(tmp, Bm, outp);
}

// Round 7
// 92.417 us; speedup vs baseline: 1.4062x; 1.4062x over previous
//
#include <hip/hip_runtime.h>
#include <cstdint>
#include <cstddef>

#define RANK 16

// ---------------------------------------------------------------------------
// Kernel 1: mix LoRA factors with per-(batch,split) skill weights.
//   Am[b][k][r] = sum_s w[b][q][s] * la[q][s][d][r],   k = q*512 + d
//                 (r-contiguous so phase A can s_load a whole 16-float row)
//   Bm[b][r][o] = 2 * sum_s w[b][q][s] * lb[q][s][r][dd], o = q*512 + dd
// (scaling = lora_alpha/rank = 2, folded into Bm)
// ---------------------------------------------------------------------------
__global__ __launch_bounds__(256) void skilled_lora_mix(
    const float* __restrict__ w,   // [8][4][8]
    const float* __restrict__ la,  // [4][8][512][16]
    const float* __restrict__ lb,  // [4][8][16][512]
    float* __restrict__ Am,        // [8][2048][16]
    float* __restrict__ Bm)        // [8][16][2048], pre-scaled by 2
{
  const int j = blockIdx.x * 256 + threadIdx.x;
  if (j < 65536) {
    const int r0 = (j & 3) * 4;
    const int k  = (j >> 2) & 2047;
    const int b  = j >> 13;
    const int q  = k >> 9;
    const int d  = k & 511;
    const float* wb = w + (b * 4 + q) * 8;
    float4 acc = make_float4(0.f, 0.f, 0.f, 0.f);
#pragma unroll
    for (int s = 0; s < 8; ++s) {
      const float ws = wb[s];
      const float4 v = *reinterpret_cast<const float4*>(
          la + (size_t)(((q * 8 + s) * 512 + d) * 16 + r0));
      acc.x = fmaf(ws, v.x, acc.x);
      acc.y = fmaf(ws, v.y, acc.y);
      acc.z = fmaf(ws, v.z, acc.z);
      acc.w = fmaf(ws, v.w, acc.w);
    }
    *reinterpret_cast<float4*>(Am + (size_t)((b * 2048 + k) * 16 + r0)) = acc;
  } else {
    const int jj = j - 65536;
    const int o  = (jj & 511) * 4;
    const int r  = (jj >> 9) & 15;
    const int b  = jj >> 13;
    const int q  = o >> 9;
    const int dd = o & 511;
    const float* wb = w + (b * 4 + q) * 8;
    float4 acc = make_float4(0.f, 0.f, 0.f, 0.f);
#pragma unroll
    for (int s = 0; s < 8; ++s) {
      const float ws = wb[s];
      const float4 v = *reinterpret_cast<const float4*>(
          lb + (size_t)(((q * 8 + s) * 16 + r) * 512 + dd));
      acc.x = fmaf(ws, v.x, acc.x);
      acc.y = fmaf(ws, v.y, acc.y);
      acc.z = fmaf(ws, v.z, acc.z);
      acc.w = fmaf(ws, v.w, acc.w);
    }
    acc.x *= 2.f; acc.y *= 2.f; acc.z *= 2.f; acc.w *= 2.f;
    *reinterpret_cast<float4*>(Bm + (size_t)((b * 16 + r) * 2048 + o)) = acc;
  }
}

// ---------------------------------------------------------------------------
// Kernel 2 (phase A): tmp[b][row][r] = sum_k X[b][row][k] * Am[b][k][r]
//
// ROUND-7 FIX: round 6 intended the A operand to ride the scalar pipe, but
// wv = tid>>6 was NOT readfirstlane'd -> pointer not provably wave-uniform ->
// compiler emitted per-lane global_load_dwordx4 (all lanes same addr) ->
// ~200cyc L2 latency serialized against each kk's 16 FMAs (VALUBusy 7.8%).
// readfirstlane(wv) makes b/kw/c/kk all scalar -> Ar[r] selects s_load.
// Per kk: 1 ds_read_b32 (conflict-free) + 16 FMA; A row in SGPRs.
// ---------------------------------------------------------------------------
#define ROWS3 64
#define KWIN3 256
#define KCH3  32
#define XS    33   // bufX row stride (odd -> (lane+kk)%32 banks, conflict-free)
#define PS    17   // part row stride (odd -> conflict-free reduce)

__global__ __launch_bounds__(512, 2) void lora_phase_a(
    const float* __restrict__ X,    // [8][2048][2048]
    const float* __restrict__ Am,   // [8][2048][16]
    float* __restrict__ tmp)        // [8][2048][16]
{
  __shared__ float lds[8 * ROWS3 * XS];   // 16896 floats = 67.6 KB

  const int tid  = threadIdx.x;
  const int lane = tid & 63;
  const int wv   = __builtin_amdgcn_readfirstlane(tid >> 6);  // 0..7, SCALAR
  const int b    = blockIdx.x >> 5;       // 8 batches x 32 row-tiles
  const int row0 = (blockIdx.x & 31) * ROWS3;
  const int kw   = wv * KWIN3;            // scalar

  float* bufX = lds + wv * (ROWS3 * XS);

  const float* Xb = X + ((size_t)(b * 2048 + row0)) * 2048 + kw;
  const float* Ab = Am + ((size_t)b * 2048 + kw) * RANK;   // scalar pointer

  const int srow = lane >> 3;             // staging: 8 rows x 8 col-groups
  const int scol = (lane & 7) * 4;

  float acc[RANK];
#pragma unroll
  for (int r = 0; r < RANK; ++r) acc[r] = 0.f;

  for (int c = 0; c < KWIN3 / KCH3; ++c) {   // 8 chunks of 32 k
    // ---- stage 64 rows x 32 k (128B contiguous per 8 lanes) ----
#pragma unroll
    for (int i = 0; i < 8; ++i) {
      const int row = i * 8 + srow;
      const float4 v = *reinterpret_cast<const float4*>(
          Xb + (size_t)row * 2048 + c * KCH3 + scol);
      float* d = bufX + row * XS + scol;
      d[0] = v.x; d[1] = v.y; d[2] = v.z; d[3] = v.w;
    }
    // wave-private buffer + same-wave in-order DS: no barrier needed.

    // ---- compute: 32 kk, A row from SGPRs (s_load), x from LDS ----
    const float* xr = bufX + lane * XS;
    const float* Ac = Ab + (size_t)(c * KCH3) * RANK;      // scalar
#pragma unroll 4
    for (int kk = 0; kk < KCH3; ++kk) {
      const float x = xr[kk];
      const float* Ar = Ac + kk * RANK;                    // scalar -> s_load
#pragma unroll
      for (int r = 0; r < RANK; ++r)
        acc[r] = fmaf(x, Ar[r], acc[r]);
    }
  }

  // ---- cross-wave reduce: park acc in (reused) LDS, then 8-way sum ----
  __syncthreads();                          // all waves done reading bufX
  float* part = lds;                        // [8 waves][64 rows][stride 17]
  {
    float* pp = part + (wv * ROWS3 + lane) * PS;
#pragma unroll
    for (int r = 0; r < RANK; ++r) pp[r] = acc[r];
  }
  __syncthreads();

#pragma unroll
  for (int v = tid; v < ROWS3 * RANK; v += 512) {
    const int row = v >> 4;
    const int r   = v & 15;
    float s = 0.f;
#pragma unroll
    for (int p = 0; p < 8; ++p) s += part[(p * ROWS3 + row) * PS + r];
    tmp[((size_t)(b * 2048 + row0 + row)) * RANK + r] = s;
  }
}

// ---------------------------------------------------------------------------
// Kernel 3 (phase B): out[b][row][o] = sum_r tmp[b][row][r] * Bm[b][r][o]
// (unchanged from round 6 — ~30 µs; revisit once phase A is near its floor)
// ---------------------------------------------------------------------------
__global__ __launch_bounds__(256, 2) void lora_phase_b(
    const float* __restrict__ tmp,  // [8][2048][16]
    const float* __restrict__ Bm,   // [8][16][2048] (pre-scaled by 2)
    float* __restrict__ out)        // [8][2048][2048]
{
  const int tid  = threadIdx.x;
  const int b    = blockIdx.x >> 7;          // 8 batches x 128 blocks
  const int oh   = (blockIdx.x >> 6) & 1;    // column half
  const int rt   = blockIdx.x & 63;          // row tile
  const int row0 = rt * 32;
  const int o0   = oh * 1024 + tid * 4;

  const float* Bb = Bm + (size_t)b * (RANK * 2048) + o0;
  float4 B4[RANK];
#pragma unroll
  for (int r = 0; r < RANK; ++r)
    B4[r] = *reinterpret_cast<const float4*>(Bb + (size_t)r * 2048);

  const float* tp = tmp + ((size_t)(b * 2048 + row0)) * RANK;
  float* op = out + ((size_t)(b * 2048 + row0)) * 2048 + o0;

#pragma unroll 4
  for (int rr = 0; rr < 32; ++rr) {
    const float4 t0 = *reinterpret_cast<const float4*>(tp + rr * RANK);
    const float4 t1 = *reinterpret_cast<const float4*>(tp + rr * RANK + 4);
    const float4 t2 = *reinterpret_cast<const float4*>(tp + rr * RANK + 8);
    const float4 t3 = *reinterpret_cast<const float4*>(tp + rr * RANK + 12);
    float4 a = make_float4(0.f, 0.f, 0.f, 0.f);
    a.x = fmaf(t0.x, B4[0].x, a.x);  a.y = fmaf(t0.x, B4[0].y, a.y);
    a.z = fmaf(t0.x, B4[0].z, a.z);  a.w = fmaf(t0.x, B4[0].w, a.w);
    a.x = fmaf(t0.y, B4[1].x, a.x);  a.y = fmaf(t0.y, B4[1].y, a.y);
    a.z = fmaf(t0.y, B4[1].z, a.z);  a.w = fmaf(t0.y, B4[1].w, a.w);
    a.x = fmaf(t0.z, B4[2].x, a.x);  a.y = fmaf(t0.z, B4[2].y, a.y);
    a.z = fmaf(t0.z, B4[2].z, a.z);  a.w = fmaf(t0.z, B4[2].w, a.w);
    a.x = fmaf(t0.w, B4[3].x, a.x);  a.y = fmaf(t0.w, B4[3].y, a.y);
    a.z = fmaf(t0.w, B4[3].z, a.z);  a.w = fmaf(t0.w, B4[3].w, a.w);
    a.x = fmaf(t1.x, B4[4].x, a.x);  a.y = fmaf(t1.x, B4[4].y, a.y);
    a.z = fmaf(t1.x, B4[4].z, a.z);  a.w = fmaf(t1.x, B4[4].w, a.w);
    a.x = fmaf(t1.y, B4[5].x, a.x);  a.y = fmaf(t1.y, B4[5].y, a.y);
    a.z = fmaf(t1.y, B4[5].z, a.z);  a.w = fmaf(t1.y, B4[5].w, a.w);
    a.x = fmaf(t1.z, B4[6].x, a.x);  a.y = fmaf(t1.z, B4[6].y, a.y);
    a.z = fmaf(t1.z, B4[6].z, a.z);  a.w = fmaf(t1.z, B4[6].w, a.w);
    a.x = fmaf(t1.w, B4[7].x, a.x);  a.y = fmaf(t1.w, B4[7].y, a.y);
    a.z = fmaf(t1.w, B4[7].z, a.z);  a.w = fmaf(t1.w, B4[7].w, a.w);
    a.x = fmaf(t2.x, B4[8].x, a.x);  a.y = fmaf(t2.x, B4[8].y, a.y);
    a.z = fmaf(t2.x, B4[8].z, a.z);  a.w = fmaf(t2.x, B4[8].w, a.w);
    a.x = fmaf(t2.y, B4[9].x, a.x);  a.y = fmaf(t2.y, B4[9].y, a.y);
    a.z = fmaf(t2.y, B4[9].z, a.z);  a.w = fmaf(t2.y, B4[9].w, a.w);
    a.x = fmaf(t2.z, B4[10].x, a.x); a.y = fmaf(t2.z, B4[10].y, a.y);
    a.z = fmaf(t2.z, B4[10].z, a.z); a.w = fmaf(t2.z, B4[10].w, a.w);
    a.x = fmaf(t2.w, B4[11].x, a.x); a.y = fmaf(t2.w, B4[11].y, a.y);
    a.z = fmaf(t2.w, B4[11].z, a.z); a.w = fmaf(t2.w, B4[11].w, a.w);
    a.x = fmaf(t3.x, B4[12].x, a.x); a.y = fmaf(t3.x, B4[12].y, a.y);
    a.z = fmaf(t3.x, B4[12].z, a.z); a.w = fmaf(t3.x, B4[12].w, a.w);
    a.x = fmaf(t3.y, B4[13].x, a.x); a.y = fmaf(t3.y, B4[13].y, a.y);
    a.z = fmaf(t3.y, B4[13].z, a.z); a.w = fmaf(t3.y, B4[13].w, a.w);
    a.x = fmaf(t3.z, B4[14].x, a.x); a.y = fmaf(t3.z, B4[14].y, a.y);
    a.z = fmaf(t3.z, B4[14].z, a.z); a.w = fmaf(t3.z, B4[14].w, a.w);
    a.x = fmaf(t3.w, B4[15].x, a.x); a.y = fmaf(t3.w, B4[15].y, a.y);
    a.z = fmaf(t3.w, B4[15].z, a.z); a.w = fmaf(t3.w, B4[15].w, a.w);
    *reinterpret_cast<float4*>(op + (size_t)rr * 2048) = a;
  }
}

// ---------------------------------------------------------------------------
extern "C" void kernel_launch(void* const* d_in, const int* in_sizes, int n_in,
                              void* d_out, int out_size, void* d_ws, size_t ws_size,
                              hipStream_t stream) {
  const float* input = (const float*)d_in[0];   // [8][2048][2048]
  const float* w     = (const float*)d_in[1];   // [8][4][8]
  const float* la    = (const float*)d_in[2];   // [4][8][512][16]
  const float* lb    = (const float*)d_in[3];   // [4][8][16][512]
  float* outp = (float*)d_out;

  float* Am  = (float*)d_ws;                    // 262144 floats (1 MB)
  float* Bm  = Am + 8 * 2048 * RANK;            // 262144 floats (1 MB)
  float* tmp = Bm + 8 * RANK * 2048;            // 262144 floats (1 MB)

  skilled_lora_mix<<<512, 256, 0, stream>>>(w, la, lb, Am, Bm);
  lora_phase_a<<<256, 512, 0, stream>>>(input, Am, tmp);
  lora_phase_b<<<1024, 256, 0, stream>>>(tmp, Bm, outp);
}

// Round 8
// 82.217 us; speedup vs baseline: 1.5806x; 1.1241x over previous
//
#include <hip/hip_runtime.h>
#include <hip/hip_bf16.h>
#include <cstdint>
#include <cstddef>

#define RANK 16

typedef __attribute__((ext_vector_type(8))) short bf16x8;   // 8 bf16 (4 VGPRs)
typedef __attribute__((ext_vector_type(4))) float f32x4;    // MFMA C/D

static __device__ __forceinline__ short f2bf(float f) {
  __hip_bfloat16 h = __float2bfloat16(f);
  return *reinterpret_cast<short*>(&h);
}

// ---------------------------------------------------------------------------
// Kernel 1: mix LoRA factors with per-(batch,split) skill weights.
//   Amt[b][r][k] = bf16( sum_s w[b][q][s] * la[q][s][d][r] ), k = q*512 + d
//                  (k-contiguous bf16 so phase A can b128-load B-fragments)
//   Bm[b][r][o]  = 2 * sum_s w[b][q][s] * lb[q][s][r][dd],   o = q*512 + dd
// (scaling = lora_alpha/rank = 2, folded into Bm; Bm stays fp32)
// ---------------------------------------------------------------------------
__global__ __launch_bounds__(256) void skilled_lora_mix(
    const float* __restrict__ w,       // [8][4][8]
    const float* __restrict__ la,      // [4][8][512][16]
    const float* __restrict__ lb,      // [4][8][16][512]
    __hip_bfloat16* __restrict__ Amt,  // [8][16][2048] bf16
    float* __restrict__ Bm)            // [8][16][2048] fp32, pre-scaled by 2
{
  const int j = blockIdx.x * 256 + threadIdx.x;
  if (j < 65536) {
    const int r0 = (j & 3) * 4;
    const int k  = (j >> 2) & 2047;
    const int b  = j >> 13;
    const int q  = k >> 9;
    const int d  = k & 511;
    const float* wb = w + (b * 4 + q) * 8;
    float4 acc = make_float4(0.f, 0.f, 0.f, 0.f);
#pragma unroll
    for (int s = 0; s < 8; ++s) {
      const float ws = wb[s];
      const float4 v = *reinterpret_cast<const float4*>(
          la + (size_t)(((q * 8 + s) * 512 + d) * 16 + r0));
      acc.x = fmaf(ws, v.x, acc.x);
      acc.y = fmaf(ws, v.y, acc.y);
      acc.z = fmaf(ws, v.z, acc.z);
      acc.w = fmaf(ws, v.w, acc.w);
    }
    // transposed bf16 store: Amt[b][r][k]
    Amt[((size_t)(b * 16 + r0 + 0)) * 2048 + k] = __float2bfloat16(acc.x);
    Amt[((size_t)(b * 16 + r0 + 1)) * 2048 + k] = __float2bfloat16(acc.y);
    Amt[((size_t)(b * 16 + r0 + 2)) * 2048 + k] = __float2bfloat16(acc.z);
    Amt[((size_t)(b * 16 + r0 + 3)) * 2048 + k] = __float2bfloat16(acc.w);
  } else {
    const int jj = j - 65536;
    const int o  = (jj & 511) * 4;
    const int r  = (jj >> 9) & 15;
    const int b  = jj >> 13;
    const int q  = o >> 9;
    const int dd = o & 511;
    const float* wb = w + (b * 4 + q) * 8;
    float4 acc = make_float4(0.f, 0.f, 0.f, 0.f);
#pragma unroll
    for (int s = 0; s < 8; ++s) {
      const float ws = wb[s];
      const float4 v = *reinterpret_cast<const float4*>(
          lb + (size_t)(((q * 8 + s) * 16 + r) * 512 + dd));
      acc.x = fmaf(ws, v.x, acc.x);
      acc.y = fmaf(ws, v.y, acc.y);
      acc.z = fmaf(ws, v.z, acc.z);
      acc.w = fmaf(ws, v.w, acc.w);
    }
    acc.x *= 2.f; acc.y *= 2.f; acc.z *= 2.f; acc.w *= 2.f;
    *reinterpret_cast<float4*>(Bm + (size_t)((b * 16 + r) * 2048 + o)) = acc;
  }
}

// ---------------------------------------------------------------------------
// Kernel 2 (phase A, MFMA): tmp[b][row][r] = sum_k X[b][row][k] * A[b][k][r]
//
// ROUND-8 REWRITE: rounds 6/7 stalled on lgkmcnt: s_load (A) and ds_read (X)
// share the counter and SMEM returns out-of-order -> every use forced
// lgkmcnt(0) full drains at 2 waves/SIMD. Now: mfma_f32_16x16x32_bf16 with
// BOTH fragments b128-loaded straight from global (vmcnt only, no LDS, no
// barriers, no s_load in the K-loop).
//
// Layout-agnostic fragments: A/B MFMA layouts are symmetric (lane%16 = m/n,
// same (lanegroup,elem)->k map). Filling A(lane=i+16g, j) = X[row0+i][k0+g*8+j]
// and B(lane=i+16g, j) = Amt[i][k0+g*8+j] contracts over a bijection of k
// regardless of the HW's internal k-permutation. C/D layout (HW-verified):
// col = lane&15 (= r), row = (lane>>4)*4 + reg.
//
// Block: 256 thr = 4 waves = 4 k-splits (512 k each) of one 16-row tile.
// Grid 1024 -> 4 blocks/CU -> 4 waves/SIMD. Epilogue: 4-way LDS reduce.
// ---------------------------------------------------------------------------
__global__ __launch_bounds__(256, 4) void lora_phase_a(
    const float* __restrict__ X,           // [8][2048][2048]
    const __hip_bfloat16* __restrict__ Amt,// [8][16][2048] bf16
    float* __restrict__ tmp)               // [8][2048][16]
{
  __shared__ float part[4][16][17];

  const int tid  = threadIdx.x;
  const int lane = tid & 63;
  const int wv   = tid >> 6;               // k-split 0..3
  const int b    = blockIdx.x >> 7;        // 8 batches x 128 row-tiles
  const int row0 = (blockIdx.x & 127) * 16;
  const int m    = lane & 15;              // row within tile / r for B-frag
  const int g    = lane >> 4;              // k-subgroup 0..3

  const float* Xp = X + ((size_t)(b * 2048 + row0 + m)) * 2048 + wv * 512 + g * 8;
  const __hip_bfloat16* Ap = Amt + ((size_t)(b * 16 + m)) * 2048 + wv * 512 + g * 8;

  f32x4 acc = {0.f, 0.f, 0.f, 0.f};
#pragma unroll 2
  for (int kg = 0; kg < 16; ++kg) {        // 16 x (K=32) = 512 k per wave
    const float4 xlo = *reinterpret_cast<const float4*>(Xp + (size_t)kg * 32);
    const float4 xhi = *reinterpret_cast<const float4*>(Xp + (size_t)kg * 32 + 4);
    bf16x8 afrag;
    afrag[0] = f2bf(xlo.x); afrag[1] = f2bf(xlo.y);
    afrag[2] = f2bf(xlo.z); afrag[3] = f2bf(xlo.w);
    afrag[4] = f2bf(xhi.x); afrag[5] = f2bf(xhi.y);
    afrag[6] = f2bf(xhi.z); afrag[7] = f2bf(xhi.w);
    const bf16x8 bfrag = *reinterpret_cast<const bf16x8*>(Ap + (size_t)kg * 32);
    acc = __builtin_amdgcn_mfma_f32_16x16x32_bf16(afrag, bfrag, acc, 0, 0, 0);
  }

  // D(lane, reg v) -> partial tmp[row=(g*4+v)][r=m]
#pragma unroll
  for (int v = 0; v < 4; ++v)
    part[wv][g * 4 + v][m] = acc[v];
  __syncthreads();

  const int row = tid >> 4;                // 0..15
  const int r   = tid & 15;
  const float s = part[0][row][r] + part[1][row][r]
                + part[2][row][r] + part[3][row][r];
  tmp[((size_t)(b * 2048 + row0 + row)) * RANK + r] = s;
}

// ---------------------------------------------------------------------------
// Kernel 3 (phase B): out[b][row][o] = sum_r tmp[b][row][r] * Bm[b][r][o]
// ROUND-8: grid 1024 -> 2048 (16 rows/block) for 8 blocks/CU of store TLP.
// B-slab in 64 VGPRs; tmp rows are block-uniform scalar loads.
// ---------------------------------------------------------------------------
__global__ __launch_bounds__(256, 2) void lora_phase_b(
    const float* __restrict__ tmp,  // [8][2048][16]
    const float* __restrict__ Bm,   // [8][16][2048] (pre-scaled by 2)
    float* __restrict__ out)        // [8][2048][2048]
{
  const int tid  = threadIdx.x;
  const int b    = blockIdx.x >> 8;          // 8 batches x 256 blocks
  const int oh   = (blockIdx.x >> 7) & 1;    // column half
  const int rt   = blockIdx.x & 127;         // row tile
  const int row0 = rt * 16;
  const int o0   = oh * 1024 + tid * 4;

  const float* Bb = Bm + (size_t)b * (RANK * 2048) + o0;
  float4 B4[RANK];
#pragma unroll
  for (int r = 0; r < RANK; ++r)
    B4[r] = *reinterpret_cast<const float4*>(Bb + (size_t)r * 2048);

  const float* tp = tmp + ((size_t)(b * 2048 + row0)) * RANK;
  float* op = out + ((size_t)(b * 2048 + row0)) * 2048 + o0;

#pragma unroll 4
  for (int rr = 0; rr < 16; ++rr) {
    const float4 t0 = *reinterpret_cast<const float4*>(tp + rr * RANK);
    const float4 t1 = *reinterpret_cast<const float4*>(tp + rr * RANK + 4);
    const float4 t2 = *reinterpret_cast<const float4*>(tp + rr * RANK + 8);
    const float4 t3 = *reinterpret_cast<const float4*>(tp + rr * RANK + 12);
    float4 a = make_float4(0.f, 0.f, 0.f, 0.f);
    a.x = fmaf(t0.x, B4[0].x, a.x);  a.y = fmaf(t0.x, B4[0].y, a.y);
    a.z = fmaf(t0.x, B4[0].z, a.z);  a.w = fmaf(t0.x, B4[0].w, a.w);
    a.x = fmaf(t0.y, B4[1].x, a.x);  a.y = fmaf(t0.y, B4[1].y, a.y);
    a.z = fmaf(t0.y, B4[1].z, a.z);  a.w = fmaf(t0.y, B4[1].w, a.w);
    a.x = fmaf(t0.z, B4[2].x, a.x);  a.y = fmaf(t0.z, B4[2].y, a.y);
    a.z = fmaf(t0.z, B4[2].z, a.z);  a.w = fmaf(t0.z, B4[2].w, a.w);
    a.x = fmaf(t0.w, B4[3].x, a.x);  a.y = fmaf(t0.w, B4[3].y, a.y);
    a.z = fmaf(t0.w, B4[3].z, a.z);  a.w = fmaf(t0.w, B4[3].w, a.w);
    a.x = fmaf(t1.x, B4[4].x, a.x);  a.y = fmaf(t1.x, B4[4].y, a.y);
    a.z = fmaf(t1.x, B4[4].z, a.z);  a.w = fmaf(t1.x, B4[4].w, a.w);
    a.x = fmaf(t1.y, B4[5].x, a.x);  a.y = fmaf(t1.y, B4[5].y, a.y);
    a.z = fmaf(t1.y, B4[5].z, a.z);  a.w = fmaf(t1.y, B4[5].w, a.w);
    a.x = fmaf(t1.z, B4[6].x, a.x);  a.y = fmaf(t1.z, B4[6].y, a.y);
    a.z = fmaf(t1.z, B4[6].z, a.z);  a.w = fmaf(t1.z, B4[6].w, a.w);
    a.x = fmaf(t1.w, B4[7].x, a.x);  a.y = fmaf(t1.w, B4[7].y, a.y);
    a.z = fmaf(t1.w, B4[7].z, a.z);  a.w = fmaf(t1.w, B4[7].w, a.w);
    a.x = fmaf(t2.x, B4[8].x, a.x);  a.y = fmaf(t2.x, B4[8].y, a.y);
    a.z = fmaf(t2.x, B4[8].z, a.z);  a.w = fmaf(t2.x, B4[8].w, a.w);
    a.x = fmaf(t2.y, B4[9].x, a.x);  a.y = fmaf(t2.y, B4[9].y, a.y);
    a.z = fmaf(t2.y, B4[9].z, a.z);  a.w = fmaf(t2.y, B4[9].w, a.w);
    a.x = fmaf(t2.z, B4[10].x, a.x); a.y = fmaf(t2.z, B4[10].y, a.y);
    a.z = fmaf(t2.z, B4[10].z, a.z); a.w = fmaf(t2.z, B4[10].w, a.w);
    a.x = fmaf(t2.w, B4[11].x, a.x); a.y = fmaf(t2.w, B4[11].y, a.y);
    a.z = fmaf(t2.w, B4[11].z, a.z); a.w = fmaf(t2.w, B4[11].w, a.w);
    a.x = fmaf(t3.x, B4[12].x, a.x); a.y = fmaf(t3.x, B4[12].y, a.y);
    a.z = fmaf(t3.x, B4[12].z, a.z); a.w = fmaf(t3.x, B4[12].w, a.w);
    a.x = fmaf(t3.y, B4[13].x, a.x); a.y = fmaf(t3.y, B4[13].y, a.y);
    a.z = fmaf(t3.y, B4[13].z, a.z); a.w = fmaf(t3.y, B4[13].w, a.w);
    a.x = fmaf(t3.z, B4[14].x, a.x); a.y = fmaf(t3.z, B4[14].y, a.y);
    a.z = fmaf(t3.z, B4[14].z, a.z); a.w = fmaf(t3.z, B4[14].w, a.w);
    a.x = fmaf(t3.w, B4[15].x, a.x); a.y = fmaf(t3.w, B4[15].y, a.y);
    a.z = fmaf(t3.w, B4[15].z, a.z); a.w = fmaf(t3.w, B4[15].w, a.w);
    *reinterpret_cast<float4*>(op + (size_t)rr * 2048) = a;
  }
}

// ---------------------------------------------------------------------------
extern "C" void kernel_launch(void* const* d_in, const int* in_sizes, int n_in,
                              void* d_out, int out_size, void* d_ws, size_t ws_size,
                              hipStream_t stream) {
  const float* input = (const float*)d_in[0];   // [8][2048][2048]
  const float* w     = (const float*)d_in[1];   // [8][4][8]
  const float* la    = (const float*)d_in[2];   // [4][8][512][16]
  const float* lb    = (const float*)d_in[3];   // [4][8][16][512]
  float* outp = (float*)d_out;

  __hip_bfloat16* Amt = (__hip_bfloat16*)d_ws;                    // 512 KB
  float* Bm  = (float*)((char*)d_ws + (size_t)8 * 16 * 2048 * 2); // 1 MB
  float* tmp = Bm + 8 * RANK * 2048;                              // 1 MB

  skilled_lora_mix<<<512, 256, 0, stream>>>(w, la, lb, Amt, Bm);
  lora_phase_a<<<1024, 256, 0, stream>>>(input, Amt, tmp);
  lora_phase_b<<<2048, 256, 0, stream>>>(tmp, Bm, outp);
}